// Round 4
// baseline (102.165 us; speedup 1.0000x reference)
//
#include <hip/hip_runtime.h>
#include <cmath>

// LinearAttention: B=4, T=512, D=192. Chunked linear-attention formulation.
// Chunk C=64, NC=8 chunks/batch. All fp32 (no fp32 MFMA on CDNA4).
// R4: 3 launches. k_prefix fused into k_out (each block recomputes its
// S_base slice from Mws; Sb tensor eliminated). k_mid scores role stages
// Q in LDS. k_out: 384 blocks, 34 KB LDS, all-resident.
#define TB  512
#define DD  192
#define NCH 8
#define CKL 64

static __device__ __forceinline__ float elu1(float v) {
    return v > 0.0f ? v + 1.0f : expf(v);
}

// ---------------------------------------------------------------------------
// K1: qkv = x @ W^T + b (2048x576, red 192), elu+1 on Q,K; split Qp/Kp/Vp.
// Tile 32(n) x 64(m), BK=64, 256 threads, 2x4 per thread. Grid (64,9)=576.
// W staged k-major in LDS with fl4-column XOR swizzle (2-way stores, free).
__global__ __launch_bounds__(256) void k_qkv(
    const float* __restrict__ x, const float* __restrict__ W,
    const float* __restrict__ bias,
    float* __restrict__ Qp, float* __restrict__ Kp, float* __restrict__ Vp)
{
    __shared__ float xs[32][68];
    __shared__ float wsT[64 * 64];     // [k][m], fl4-swizzled columns
    const int tid = threadIdx.x;
    const int n0 = blockIdx.x * 32;
    const int m0 = blockIdx.y * 64;
    const int a  = tid >> 4;           // 0..15
    const int c  = tid & 15;           // 0..15

    float acc[2][4];
    #pragma unroll
    for (int r = 0; r < 2; ++r)
        #pragma unroll
        for (int s = 0; s < 4; ++s) acc[r][s] = 0.f;

    for (int kb = 0; kb < DD; kb += 64) {
        #pragma unroll
        for (int p = 0; p < 2; ++p) {
            int q = p * 256 + tid;             // 32 rows x 16 fl4
            int row = q >> 4, c4 = (q & 15) * 4;
            *(float4*)&xs[row][c4] = *(const float4*)&x[(n0 + row) * DD + kb + c4];
        }
        #pragma unroll
        for (int p = 0; p < 4; ++p) {
            int q = p * 256 + tid;             // 64 rows x 16 fl4
            int mrow = q >> 4, kidx = q & 15;  // kidx = k fl4-group
            float4 wv = *(const float4*)&W[(m0 + mrow) * DD + kb + kidx * 4];
            int g = (mrow >> 2) ^ kidx;        // swizzled fl4 column group
            int pcol = g * 4 + (mrow & 3);
            wsT[(kidx * 4 + 0) * 64 + pcol] = wv.x;
            wsT[(kidx * 4 + 1) * 64 + pcol] = wv.y;
            wsT[(kidx * 4 + 2) * 64 + pcol] = wv.z;
            wsT[(kidx * 4 + 3) * 64 + pcol] = wv.w;
        }
        __syncthreads();
        #pragma unroll
        for (int kk = 0; kk < 64; kk += 4) {
            float4 xv0 = *(const float4*)&xs[a][kk];
            float4 xv1 = *(const float4*)&xs[16 + a][kk];
            const int g = (c ^ ((kk >> 2) & 15)) * 4;
            float x0[4] = {xv0.x, xv0.y, xv0.z, xv0.w};
            float x1[4] = {xv1.x, xv1.y, xv1.z, xv1.w};
            #pragma unroll
            for (int j = 0; j < 4; ++j) {
                float4 wk = *(const float4*)&wsT[(kk + j) * 64 + g];
                acc[0][0] += x0[j] * wk.x; acc[0][1] += x0[j] * wk.y;
                acc[0][2] += x0[j] * wk.z; acc[0][3] += x0[j] * wk.w;
                acc[1][0] += x1[j] * wk.x; acc[1][1] += x1[j] * wk.y;
                acc[1][2] += x1[j] * wk.z; acc[1][3] += x1[j] * wk.w;
            }
        }
        __syncthreads();
    }

    const int reg  = m0 / DD;              // 0:Q 1:K 2:V (tiles never straddle)
    float* dst = (reg == 0) ? Qp : (reg == 1 ? Kp : Vp);
    const int mloc = (m0 % DD) + c * 4;
    #pragma unroll
    for (int r = 0; r < 2; ++r) {
        int n = n0 + r * 16 + a;
        float v0 = acc[r][0] + bias[m0 + c * 4 + 0];
        float v1 = acc[r][1] + bias[m0 + c * 4 + 1];
        float v2 = acc[r][2] + bias[m0 + c * 4 + 2];
        float v3 = acc[r][3] + bias[m0 + c * 4 + 3];
        if (reg < 2) { v0 = elu1(v0); v1 = elu1(v1); v2 = elu1(v2); v3 = elu1(v3); }
        *(float4*)&dst[n * DD + mloc] = make_float4(v0, v1, v2, v3);
    }
}

// ---------------------------------------------------------------------------
// K2 (fused): grid (32 bc, 10 role).
//   role 0..5: chunksum  M_c[i][j] = sum_t K[t][i]V[t][j], 96i x 64j tile
//              (ih=role/3, jh=role%3); z_c[i] for jh==0.
//   role 6..9: scores    A = (Q K^T) causal rows tq*16..+15, red 192;
//              row-sums -> denws. Q staged in LDS (burst).
__global__ __launch_bounds__(256) void k_mid(
    const float* __restrict__ Kp, const float* __restrict__ Vp,
    const float* __restrict__ Qp,
    float* __restrict__ Mws, float* __restrict__ zws,
    float* __restrict__ Aws, float* __restrict__ denws)
{
    __shared__ float sm[64 * 196 + 16 * 196];   // 61.3 KB union
    const int tid  = threadIdx.x;
    const int bc   = blockIdx.x;
    const int role = blockIdx.y;
    const int base = bc * CKL;

    if (role < 6) {
        // ---- chunksum ----
        const int ih = role / 3, jh = role % 3;
        float (*Ks)[100] = (float (*)[100])sm;          // 64 x 100
        float (*Vs)[68]  = (float (*)[68])(sm + 6400);  // 64 x 68

        #pragma unroll
        for (int p = 0; p < 6; ++p) {
            int q = p * 256 + tid;       // 64 rows x 24 fl4
            int row = q / 24, c4 = (q % 24) * 4;
            *(float4*)&Ks[row][c4] = *(const float4*)&Kp[(base + row) * DD + ih * 96 + c4];
        }
        #pragma unroll
        for (int p = 0; p < 4; ++p) {
            int q = p * 256 + tid;       // 64 rows x 16 fl4
            int row = q >> 4, c4 = (q & 15) * 4;
            *(float4*)&Vs[row][c4] = *(const float4*)&Vp[(base + row) * DD + jh * 64 + c4];
        }
        __syncthreads();

        const int ig = tid >> 4, jg = tid & 15;
        const int iL = ig * 6;
        float acc[6][4];
        #pragma unroll
        for (int i = 0; i < 6; ++i)
            #pragma unroll
            for (int j = 0; j < 4; ++j) acc[i][j] = 0.f;

        #pragma unroll 4
        for (int t = 0; t < CKL; ++t) {
            float4 v = *(const float4*)&Vs[t][jg * 4];
            float2 k0 = *(const float2*)&Ks[t][iL + 0];
            float2 k1 = *(const float2*)&Ks[t][iL + 2];
            float2 k2 = *(const float2*)&Ks[t][iL + 4];
            float kv[6] = {k0.x, k0.y, k1.x, k1.y, k2.x, k2.y};
            #pragma unroll
            for (int i = 0; i < 6; ++i) {
                acc[i][0] += kv[i] * v.x;
                acc[i][1] += kv[i] * v.y;
                acc[i][2] += kv[i] * v.z;
                acc[i][3] += kv[i] * v.w;
            }
        }

        float* Mout = Mws + (size_t)bc * DD * DD;
        const int j0 = jh * 64 + jg * 4;
        #pragma unroll
        for (int i = 0; i < 6; ++i)
            *(float4*)&Mout[(ih * 96 + iL + i) * DD + j0] =
                make_float4(acc[i][0], acc[i][1], acc[i][2], acc[i][3]);

        if (jh == 0 && tid < 96) {
            float s = 0.f;
            #pragma unroll 8
            for (int t = 0; t < CKL; ++t) s += Ks[t][tid];
            zws[bc * DD + ih * 96 + tid] = s;
        }
    } else {
        // ---- scores ----
        const int tq = role - 6;
        const int tbase = tq * 16;
        float (*Ks)[196] = (float (*)[196])sm;               // 64 x 196
        float (*Qs)[196] = (float (*)[196])(sm + 64 * 196);  // 16 x 196

        #pragma unroll
        for (int p = 0; p < 12; ++p) {
            int q = p * 256 + tid;       // 64 rows x 48 fl4
            int row = q / 48, c4 = (q % 48) * 4;
            *(float4*)&Ks[row][c4] = *(const float4*)&Kp[(base + row) * DD + c4];
        }
        #pragma unroll
        for (int p = 0; p < 3; ++p) {
            int q = p * 256 + tid;       // 16 rows x 48 fl4
            int row = q / 48, c4 = (q % 48) * 4;
            *(float4*)&Qs[row][c4] = *(const float4*)&Qp[(base + tbase + row) * DD + c4];
        }
        __syncthreads();

        const int trow = tid >> 4, tc = tid & 15;
        const int tg = tbase + trow;
        float acc[4];
        #pragma unroll
        for (int s = 0; s < 4; ++s) acc[s] = 0.f;

        #pragma unroll 4
        for (int k = 0; k < DD; k += 4) {
            float4 qv = *(const float4*)&Qs[trow][k];  // 4-addr broadcast, free
            #pragma unroll
            for (int s = 0; s < 4; ++s) {
                float4 kv = *(const float4*)&Ks[tc * 4 + s][k];
                acc[s] += qv.x*kv.x + qv.y*kv.y + qv.z*kv.z + qv.w*kv.w;
            }
        }

        float av[4], psum = 0.f;
        #pragma unroll
        for (int s = 0; s < 4; ++s) {
            int tau = tc * 4 + s;
            av[s] = (tau <= tg) ? acc[s] : 0.f;        // inclusive causal mask
            psum += av[s];
        }
        *(float4*)&Aws[bc * 4096 + tg * 64 + tc * 4] =
            make_float4(av[0], av[1], av[2], av[3]);
        #pragma unroll
        for (int off = 1; off < 16; off <<= 1)
            psum += __shfl_xor(psum, off, 16);
        if (tc == 0) denws[base + tg] = psum;
    }
}

// ---------------------------------------------------------------------------
// K3 (fused prefix + output): grid (32 bc, 12 lq), 256 thr = 64 t x 4 lg.
// Block recomputes S_base slice = S0 + sum_{cc<c} M[cc] (registers -> LDS),
// Z_base likewise; c==7 blocks also emit S_last (+M[7]) and Z_last.
// O[t][l] = sum_tau A[t][tau] V[tau][l] + sum_i Q[t][i] Sbase[i][l];
// den[t] = denws[t] + sum_i Q[t][i] Zbase[i] + 1e-5; out = O/den.
// LDS: As 64x68 (17.4K) + Ss 192x16 (12K) + Vs 64x16 (4K) + Zs (0.77K)
//      = 34.2 KB -> 4 blocks/CU; 384 blocks fully resident.
__global__ __launch_bounds__(256) void k_out(
    const float* __restrict__ Qp, const float* __restrict__ Vp,
    const float* __restrict__ Aws, const float* __restrict__ denws,
    const float* __restrict__ Mws, const float* __restrict__ zws,
    const float* __restrict__ S0, const float* __restrict__ Z0,
    float* __restrict__ out, float* __restrict__ Slast, float* __restrict__ Zlast)
{
    __shared__ float As[64][68];
    __shared__ float Ss[DD][16];
    __shared__ float Vs[CKL][16];
    __shared__ float Zs[DD];
    const int tid = threadIdx.x;
    const int bc  = blockIdx.x;
    const int lq  = blockIdx.y;
    const int b   = bc >> 3, c = bc & 7;
    const int base = bc * CKL;
    const int lofs = lq * 16;

    // ---- stage A (64x64, already causal-masked) ----
    #pragma unroll
    for (int p = 0; p < 4; ++p) {
        int q = p * 256 + tid;           // 64 rows x 16 fl4
        int row = q >> 4, c4 = (q & 15) * 4;
        *(float4*)&As[row][c4] = *(const float4*)&Aws[bc * 4096 + row * 64 + c4];
    }
    // ---- stage V slice (64 x 16) ----
    {
        int row = tid >> 2, c4 = (tid & 3) * 4;
        *(float4*)&Vs[row][c4] = *(const float4*)&Vp[(base + row) * DD + lofs + c4];
    }
    // ---- S_base slice: S0 + sum_{cc<c} M[cc]; c==7 also S_last ----
    {
        float4 r[3];
        #pragma unroll
        for (int p = 0; p < 3; ++p) {
            int q = p * 256 + tid;       // 192 rows x 4 fl4
            int row = q >> 2, c4 = (q & 3) * 4;
            r[p] = *(const float4*)&S0[(size_t)b * DD * DD + row * DD + lofs + c4];
        }
        for (int cc = 0; cc < c; ++cc) {
            const float* Mc = Mws + (size_t)(b * NCH + cc) * DD * DD;
            #pragma unroll
            for (int p = 0; p < 3; ++p) {
                int q = p * 256 + tid;
                int row = q >> 2, c4 = (q & 3) * 4;
                float4 m = *(const float4*)&Mc[row * DD + lofs + c4];
                r[p].x += m.x; r[p].y += m.y; r[p].z += m.z; r[p].w += m.w;
            }
        }
        #pragma unroll
        for (int p = 0; p < 3; ++p) {
            int q = p * 256 + tid;
            int row = q >> 2, c4 = (q & 3) * 4;
            *(float4*)&Ss[row][c4] = r[p];
        }
        if (c == NCH - 1) {
            const float* M7 = Mws + (size_t)(b * NCH + 7) * DD * DD;
            #pragma unroll
            for (int p = 0; p < 3; ++p) {
                int q = p * 256 + tid;
                int row = q >> 2, c4 = (q & 3) * 4;
                float4 m = *(const float4*)&M7[row * DD + lofs + c4];
                *(float4*)&Slast[(size_t)b * DD * DD + row * DD + lofs + c4] =
                    make_float4(r[p].x + m.x, r[p].y + m.y, r[p].z + m.z, r[p].w + m.w);
            }
        }
    }
    // ---- Z_base: Z0 + sum_{cc<c} zws[cc]; c==7 (lq==0) also Z_last ----
    if (tid < DD) {
        float z = Z0[b * DD + tid];
        for (int cc = 0; cc < c; ++cc)
            z += zws[(b * NCH + cc) * DD + tid];
        Zs[tid] = z;
        if (c == NCH - 1 && lq == 0)
            Zlast[b * DD + tid] = z + zws[(b * NCH + 7) * DD + tid];
    }
    __syncthreads();

    const int t  = tid >> 2;             // 0..63
    const int lg = (tid & 3) * 4;        // 0,4,8,12
    float ax = 0.f, ay = 0.f, az = 0.f, aw = 0.f, dacc = 0.f;

    // intra-chunk: sum_tau A[t][tau] * V[tau][l]
    #pragma unroll 16
    for (int tau = 0; tau < CKL; ++tau) {
        float a = As[t][tau];            // 2-way (free) x4 broadcast
        float4 v = *(const float4*)&Vs[tau][lg];
        ax += a * v.x; ay += a * v.y; az += a * v.z; aw += a * v.w;
    }

    // cross-chunk: sum_i Q[t][i] * (Sbase[i][l], Zbase[i])
    const float* Qrow = Qp + (size_t)(base + t) * DD;
    #pragma unroll 4
    for (int i = 0; i < DD; i += 4) {
        float4 qv = *(const float4*)&Qrow[i];   // global, 16 addr x4 broadcast
        float qq[4] = {qv.x, qv.y, qv.z, qv.w};
        #pragma unroll
        for (int u = 0; u < 4; ++u) {
            float4 s = *(const float4*)&Ss[i + u][lg];
            ax += qq[u] * s.x; ay += qq[u] * s.y;
            az += qq[u] * s.z; aw += qq[u] * s.w;
            dacc += qq[u] * Zs[i + u];
        }
    }

    float den = denws[base + t] + dacc + 1e-5f;
    float inv = 1.f / den;
    *(float4*)&out[(size_t)(base + t) * DD + lofs + lg] =
        make_float4(ax * inv, ay * inv, az * inv, aw * inv);
}

// ---------------------------------------------------------------------------
extern "C" void kernel_launch(void* const* d_in, const int* in_sizes, int n_in,
                              void* d_out, int out_size, void* d_ws, size_t ws_size,
                              hipStream_t stream)
{
    const float* x  = (const float*)d_in[0];  // (4,512,192)
    const float* W  = (const float*)d_in[1];  // (576,192)
    const float* bb = (const float*)d_in[2];  // (576,)
    const float* S0 = (const float*)d_in[3];  // (4,1,192,192)
    const float* Z0 = (const float*)d_in[4];  // (4,1,192)

    float* out   = (float*)d_out;                       // (4,512,192)
    float* Slast = out + (size_t)4 * TB * DD;           // (4,192*192)
    float* Zlast = Slast + (size_t)4 * DD * DD;         // (4,192)

    float* ws   = (float*)d_ws;
    float* Qp   = ws;                                   // 4*512*192
    float* Kp   = Qp + (size_t)4 * TB * DD;
    float* Vp   = Kp + (size_t)4 * TB * DD;
    float* Mws  = Vp + (size_t)4 * TB * DD;             // 32 * 192*192
    float* zws  = Mws + (size_t)4 * NCH * DD * DD;      // 32 * 192
    float* Aws  = zws + (size_t)4 * NCH * DD;           // 32 * 64*64
    float* denw = Aws + (size_t)4 * NCH * CKL * CKL;    // 4*512

    k_qkv<<<dim3(64, 9),  256, 0, stream>>>(x, W, bb, Qp, Kp, Vp);
    k_mid<<<dim3(32, 10), 256, 0, stream>>>(Kp, Vp, Qp, Mws, zws, Aws, denw);
    k_out<<<dim3(32, 12), 256, 0, stream>>>(Qp, Vp, Aws, denw, Mws, zws,
                                            S0, Z0, out, Slast, Zlast);
}

// Round 5
// 95.264 us; speedup vs baseline: 1.0724x; 1.0724x over previous
//
#include <hip/hip_runtime.h>
#include <cmath>

// LinearAttention: B=4, T=512, D=192. Chunked linear-attention formulation.
// Chunk C=64, NC=8 chunks/batch.
// R5: k_qkv rewritten with bf16 MFMA (16x16x32). x,W are k-contiguous so
// A/B fragments are single b128 LDS reads (layout [r=lane&15][k=quad*8+j]).
// One staging phase + one barrier. k_mid/k_out stay fp32 VALU.
// NOTE: dur_us includes ~2x44us harness re-poison fill of the 268MB ws;
// kernel-side budget is only ~14us of the measured ~102.
#define TB  512
#define DD  192
#define NCH 8
#define CKL 64

static __device__ __forceinline__ float elu1(float v) {
    return v > 0.0f ? v + 1.0f : expf(v);
}

typedef __attribute__((ext_vector_type(8))) __bf16 bf16x8;
typedef __attribute__((ext_vector_type(4))) float floatx4;

static __device__ __forceinline__ __bf16 f2bf(float f) {
    unsigned u = __builtin_bit_cast(unsigned, f);
    u += 0x7FFF + ((u >> 16) & 1);               // round-to-nearest-even
    unsigned short h = (unsigned short)(u >> 16);
    return __builtin_bit_cast(__bf16, h);
}

// ---------------------------------------------------------------------------
// K1: qkv = x @ W^T + b (2048x576, red 192), elu+1 on Q,K; split Qp/Kp/Vp.
// bf16 MFMA 16x16x32. Block tile 64n x 64m, 256 thr = 4 waves, each wave a
// 32x32 quadrant = 2x2 mfma tiles x 6 k-steps. Grid (32, 9) = 288 blocks.
// LDS 2 x 64x200 bf16 = 51.2 KB (pad 200: quad-stride 400B -> 2-way, free).
__global__ __launch_bounds__(256) void k_qkv(
    const float* __restrict__ x, const float* __restrict__ W,
    const float* __restrict__ bias,
    float* __restrict__ Qp, float* __restrict__ Kp, float* __restrict__ Vp)
{
    __shared__ __bf16 xs[64][200];
    __shared__ __bf16 wsb[64][200];
    const int tid = threadIdx.x;
    const int n0 = blockIdx.x * 64;
    const int m0 = blockIdx.y * 64;

    // ---- stage x,W tiles: fp32 global -> bf16 LDS (12 fl4 each per thread)
    #pragma unroll
    for (int p = 0; p < 12; ++p) {
        int q = p * 256 + tid;               // 64 rows x 48 fl4
        int row = q / 48, c4 = (q % 48) * 4;
        float4 xv = *(const float4*)&x[(n0 + row) * DD + c4];
        xs[row][c4 + 0] = f2bf(xv.x); xs[row][c4 + 1] = f2bf(xv.y);
        xs[row][c4 + 2] = f2bf(xv.z); xs[row][c4 + 3] = f2bf(xv.w);
        float4 wv = *(const float4*)&W[(m0 + row) * DD + c4];
        wsb[row][c4 + 0] = f2bf(wv.x); wsb[row][c4 + 1] = f2bf(wv.y);
        wsb[row][c4 + 2] = f2bf(wv.z); wsb[row][c4 + 3] = f2bf(wv.w);
    }
    __syncthreads();

    const int wv_  = tid >> 6;               // wave 0..3
    const int nh   = (wv_ & 1) * 32;         // n-quadrant
    const int mh   = (wv_ >> 1) * 32;        // m-quadrant
    const int lane = tid & 63;
    const int r16  = lane & 15;
    const int quad = lane >> 4;

    floatx4 acc[2][2];
    #pragma unroll
    for (int tn = 0; tn < 2; ++tn)
        #pragma unroll
        for (int tm = 0; tm < 2; ++tm)
            acc[tn][tm] = (floatx4){0.f, 0.f, 0.f, 0.f};

    #pragma unroll
    for (int ks = 0; ks < 6; ++ks) {
        const int k0 = ks * 32 + quad * 8;
        bf16x8 a0 = *(const bf16x8*)&xs[nh + 0  + r16][k0];
        bf16x8 a1 = *(const bf16x8*)&xs[nh + 16 + r16][k0];
        bf16x8 b0 = *(const bf16x8*)&wsb[mh + 0  + r16][k0];
        bf16x8 b1 = *(const bf16x8*)&wsb[mh + 16 + r16][k0];
        acc[0][0] = __builtin_amdgcn_mfma_f32_16x16x32_bf16(a0, b0, acc[0][0], 0, 0, 0);
        acc[0][1] = __builtin_amdgcn_mfma_f32_16x16x32_bf16(a0, b1, acc[0][1], 0, 0, 0);
        acc[1][0] = __builtin_amdgcn_mfma_f32_16x16x32_bf16(a1, b0, acc[1][0], 0, 0, 0);
        acc[1][1] = __builtin_amdgcn_mfma_f32_16x16x32_bf16(a1, b1, acc[1][1], 0, 0, 0);
    }

    // ---- epilogue: C/D layout col=lane&15, row=quad*4+j ----
    const int reg  = m0 / DD;                // 0:Q 1:K 2:V (tiles never straddle)
    float* dst = (reg == 0) ? Qp : (reg == 1 ? Kp : Vp);
    const int mbase = m0 % DD;
    #pragma unroll
    for (int tn = 0; tn < 2; ++tn) {
        #pragma unroll
        for (int tm = 0; tm < 2; ++tm) {
            const int mloc = mh + tm * 16 + r16;
            const float bs = bias[m0 + mloc];
            #pragma unroll
            for (int j = 0; j < 4; ++j) {
                const int nloc = nh + tn * 16 + quad * 4 + j;
                float v = acc[tn][tm][j] + bs;
                if (reg < 2) v = elu1(v);
                dst[(size_t)(n0 + nloc) * DD + mbase + mloc] = v;
            }
        }
    }
}

// ---------------------------------------------------------------------------
// K2 (fused): grid (32 bc, 10 role).
//   role 0..5: chunksum  M_c[i][j] = sum_t K[t][i]V[t][j], 96i x 64j tile
//              (ih=role/3, jh=role%3); z_c[i] for jh==0.
//   role 6..9: scores    A = (Q K^T) causal rows tq*16..+15, red 192;
//              row-sums -> denws. Q staged in LDS (burst).
__global__ __launch_bounds__(256) void k_mid(
    const float* __restrict__ Kp, const float* __restrict__ Vp,
    const float* __restrict__ Qp,
    float* __restrict__ Mws, float* __restrict__ zws,
    float* __restrict__ Aws, float* __restrict__ denws)
{
    __shared__ float sm[64 * 196 + 16 * 196];   // 61.3 KB union
    const int tid  = threadIdx.x;
    const int bc   = blockIdx.x;
    const int role = blockIdx.y;
    const int base = bc * CKL;

    if (role < 6) {
        // ---- chunksum ----
        const int ih = role / 3, jh = role % 3;
        float (*Ks)[100] = (float (*)[100])sm;          // 64 x 100
        float (*Vs)[68]  = (float (*)[68])(sm + 6400);  // 64 x 68

        #pragma unroll
        for (int p = 0; p < 6; ++p) {
            int q = p * 256 + tid;       // 64 rows x 24 fl4
            int row = q / 24, c4 = (q % 24) * 4;
            *(float4*)&Ks[row][c4] = *(const float4*)&Kp[(base + row) * DD + ih * 96 + c4];
        }
        #pragma unroll
        for (int p = 0; p < 4; ++p) {
            int q = p * 256 + tid;       // 64 rows x 16 fl4
            int row = q >> 4, c4 = (q & 15) * 4;
            *(float4*)&Vs[row][c4] = *(const float4*)&Vp[(base + row) * DD + jh * 64 + c4];
        }
        __syncthreads();

        const int ig = tid >> 4, jg = tid & 15;
        const int iL = ig * 6;
        float acc[6][4];
        #pragma unroll
        for (int i = 0; i < 6; ++i)
            #pragma unroll
            for (int j = 0; j < 4; ++j) acc[i][j] = 0.f;

        #pragma unroll 4
        for (int t = 0; t < CKL; ++t) {
            float4 v = *(const float4*)&Vs[t][jg * 4];
            float2 k0 = *(const float2*)&Ks[t][iL + 0];
            float2 k1 = *(const float2*)&Ks[t][iL + 2];
            float2 k2 = *(const float2*)&Ks[t][iL + 4];
            float kv[6] = {k0.x, k0.y, k1.x, k1.y, k2.x, k2.y};
            #pragma unroll
            for (int i = 0; i < 6; ++i) {
                acc[i][0] += kv[i] * v.x;
                acc[i][1] += kv[i] * v.y;
                acc[i][2] += kv[i] * v.z;
                acc[i][3] += kv[i] * v.w;
            }
        }

        float* Mout = Mws + (size_t)bc * DD * DD;
        const int j0 = jh * 64 + jg * 4;
        #pragma unroll
        for (int i = 0; i < 6; ++i)
            *(float4*)&Mout[(ih * 96 + iL + i) * DD + j0] =
                make_float4(acc[i][0], acc[i][1], acc[i][2], acc[i][3]);

        if (jh == 0 && tid < 96) {
            float s = 0.f;
            #pragma unroll 8
            for (int t = 0; t < CKL; ++t) s += Ks[t][tid];
            zws[bc * DD + ih * 96 + tid] = s;
        }
    } else {
        // ---- scores ----
        const int tq = role - 6;
        const int tbase = tq * 16;
        float (*Ks)[196] = (float (*)[196])sm;               // 64 x 196
        float (*Qs)[196] = (float (*)[196])(sm + 64 * 196);  // 16 x 196

        #pragma unroll
        for (int p = 0; p < 12; ++p) {
            int q = p * 256 + tid;       // 64 rows x 48 fl4
            int row = q / 48, c4 = (q % 48) * 4;
            *(float4*)&Ks[row][c4] = *(const float4*)&Kp[(base + row) * DD + c4];
        }
        #pragma unroll
        for (int p = 0; p < 3; ++p) {
            int q = p * 256 + tid;       // 16 rows x 48 fl4
            int row = q / 48, c4 = (q % 48) * 4;
            *(float4*)&Qs[row][c4] = *(const float4*)&Qp[(base + tbase + row) * DD + c4];
        }
        __syncthreads();

        const int trow = tid >> 4, tc = tid & 15;
        const int tg = tbase + trow;
        float acc[4];
        #pragma unroll
        for (int s = 0; s < 4; ++s) acc[s] = 0.f;

        #pragma unroll 4
        for (int k = 0; k < DD; k += 4) {
            float4 qv = *(const float4*)&Qs[trow][k];  // 4-addr broadcast, free
            #pragma unroll
            for (int s = 0; s < 4; ++s) {
                float4 kv = *(const float4*)&Ks[tc * 4 + s][k];
                acc[s] += qv.x*kv.x + qv.y*kv.y + qv.z*kv.z + qv.w*kv.w;
            }
        }

        float av[4], psum = 0.f;
        #pragma unroll
        for (int s = 0; s < 4; ++s) {
            int tau = tc * 4 + s;
            av[s] = (tau <= tg) ? acc[s] : 0.f;        // inclusive causal mask
            psum += av[s];
        }
        *(float4*)&Aws[bc * 4096 + tg * 64 + tc * 4] =
            make_float4(av[0], av[1], av[2], av[3]);
        #pragma unroll
        for (int off = 1; off < 16; off <<= 1)
            psum += __shfl_xor(psum, off, 16);
        if (tc == 0) denws[base + tg] = psum;
    }
}

// ---------------------------------------------------------------------------
// K3 (fused prefix + output): grid (32 bc, 12 lq), 256 thr = 64 t x 4 lg.
// Block recomputes S_base slice = S0 + sum_{cc<c} M[cc] (registers -> LDS),
// Z_base likewise; c==7 blocks also emit S_last (+M[7]) and Z_last.
__global__ __launch_bounds__(256) void k_out(
    const float* __restrict__ Qp, const float* __restrict__ Vp,
    const float* __restrict__ Aws, const float* __restrict__ denws,
    const float* __restrict__ Mws, const float* __restrict__ zws,
    const float* __restrict__ S0, const float* __restrict__ Z0,
    float* __restrict__ out, float* __restrict__ Slast, float* __restrict__ Zlast)
{
    __shared__ float As[64][68];
    __shared__ float Ss[DD][16];
    __shared__ float Vs[CKL][16];
    __shared__ __align__(16) float Zs[DD];
    const int tid = threadIdx.x;
    const int bc  = blockIdx.x;
    const int lq  = blockIdx.y;
    const int b   = bc >> 3, c = bc & 7;
    const int base = bc * CKL;
    const int lofs = lq * 16;

    // ---- stage A (64x64, already causal-masked) ----
    #pragma unroll
    for (int p = 0; p < 4; ++p) {
        int q = p * 256 + tid;           // 64 rows x 16 fl4
        int row = q >> 4, c4 = (q & 15) * 4;
        *(float4*)&As[row][c4] = *(const float4*)&Aws[bc * 4096 + row * 64 + c4];
    }
    // ---- stage V slice (64 x 16) ----
    {
        int row = tid >> 2, c4 = (tid & 3) * 4;
        *(float4*)&Vs[row][c4] = *(const float4*)&Vp[(base + row) * DD + lofs + c4];
    }
    // ---- S_base slice: S0 + sum_{cc<c} M[cc]; c==7 also S_last ----
    {
        float4 r[3];
        #pragma unroll
        for (int p = 0; p < 3; ++p) {
            int q = p * 256 + tid;       // 192 rows x 4 fl4
            int row = q >> 2, c4 = (q & 3) * 4;
            r[p] = *(const float4*)&S0[(size_t)b * DD * DD + row * DD + lofs + c4];
        }
        for (int cc = 0; cc < c; ++cc) {
            const float* Mc = Mws + (size_t)(b * NCH + cc) * DD * DD;
            #pragma unroll
            for (int p = 0; p < 3; ++p) {
                int q = p * 256 + tid;
                int row = q >> 2, c4 = (q & 3) * 4;
                float4 m = *(const float4*)&Mc[row * DD + lofs + c4];
                r[p].x += m.x; r[p].y += m.y; r[p].z += m.z; r[p].w += m.w;
            }
        }
        #pragma unroll
        for (int p = 0; p < 3; ++p) {
            int q = p * 256 + tid;
            int row = q >> 2, c4 = (q & 3) * 4;
            *(float4*)&Ss[row][c4] = r[p];
        }
        if (c == NCH - 1) {
            const float* M7 = Mws + (size_t)(b * NCH + 7) * DD * DD;
            #pragma unroll
            for (int p = 0; p < 3; ++p) {
                int q = p * 256 + tid;
                int row = q >> 2, c4 = (q & 3) * 4;
                float4 m = *(const float4*)&M7[row * DD + lofs + c4];
                *(float4*)&Slast[(size_t)b * DD * DD + row * DD + lofs + c4] =
                    make_float4(r[p].x + m.x, r[p].y + m.y, r[p].z + m.z, r[p].w + m.w);
            }
        }
    }
    // ---- Z_base: Z0 + sum_{cc<c} zws[cc]; c==7 (lq==0) also Z_last ----
    if (tid < DD) {
        float z = Z0[b * DD + tid];
        for (int cc = 0; cc < c; ++cc)
            z += zws[(b * NCH + cc) * DD + tid];
        Zs[tid] = z;
        if (c == NCH - 1 && lq == 0)
            Zlast[b * DD + tid] = z + zws[(b * NCH + 7) * DD + tid];
    }
    __syncthreads();

    const int t  = tid >> 2;             // 0..63
    const int lg = (tid & 3) * 4;        // 0,4,8,12
    float ax = 0.f, ay = 0.f, az = 0.f, aw = 0.f, dacc = 0.f;

    // intra-chunk: sum_tau A[t][tau] * V[tau][l]
    #pragma unroll 16
    for (int tau = 0; tau < CKL; ++tau) {
        float a = As[t][tau];            // 2-way (free) x4 broadcast
        float4 v = *(const float4*)&Vs[tau][lg];
        ax += a * v.x; ay += a * v.y; az += a * v.z; aw += a * v.w;
    }

    // cross-chunk: sum_i Q[t][i] * (Sbase[i][l], Zbase[i])
    const float* Qrow = Qp + (size_t)(base + t) * DD;
    #pragma unroll 4
    for (int i = 0; i < DD; i += 4) {
        float4 qv = *(const float4*)&Qrow[i];   // global, 16 addr x4 broadcast
        float4 zv = *(const float4*)&Zs[i];     // LDS b128 broadcast
        dacc += qv.x*zv.x + qv.y*zv.y + qv.z*zv.z + qv.w*zv.w;
        float qq[4] = {qv.x, qv.y, qv.z, qv.w};
        #pragma unroll
        for (int u = 0; u < 4; ++u) {
            float4 s = *(const float4*)&Ss[i + u][lg];
            ax += qq[u] * s.x; ay += qq[u] * s.y;
            az += qq[u] * s.z; aw += qq[u] * s.w;
        }
    }

    float den = denws[base + t] + dacc + 1e-5f;
    float inv = 1.f / den;
    *(float4*)&out[(size_t)(base + t) * DD + lofs + lg] =
        make_float4(ax * inv, ay * inv, az * inv, aw * inv);
}

// ---------------------------------------------------------------------------
extern "C" void kernel_launch(void* const* d_in, const int* in_sizes, int n_in,
                              void* d_out, int out_size, void* d_ws, size_t ws_size,
                              hipStream_t stream)
{
    const float* x  = (const float*)d_in[0];  // (4,512,192)
    const float* W  = (const float*)d_in[1];  // (576,192)
    const float* bb = (const float*)d_in[2];  // (576,)
    const float* S0 = (const float*)d_in[3];  // (4,1,192,192)
    const float* Z0 = (const float*)d_in[4];  // (4,1,192)

    float* out   = (float*)d_out;                       // (4,512,192)
    float* Slast = out + (size_t)4 * TB * DD;           // (4,192*192)
    float* Zlast = Slast + (size_t)4 * DD * DD;         // (4,192)

    float* ws   = (float*)d_ws;
    float* Qp   = ws;                                   // 4*512*192
    float* Kp   = Qp + (size_t)4 * TB * DD;
    float* Vp   = Kp + (size_t)4 * TB * DD;
    float* Mws  = Vp + (size_t)4 * TB * DD;             // 32 * 192*192
    float* zws  = Mws + (size_t)4 * NCH * DD * DD;      // 32 * 192
    float* Aws  = zws + (size_t)4 * NCH * DD;           // 32 * 64*64
    float* denw = Aws + (size_t)4 * NCH * CKL * CKL;    // 4*512

    k_qkv<<<dim3(32, 9),  256, 0, stream>>>(x, W, bb, Qp, Kp, Vp);
    k_mid<<<dim3(32, 10), 256, 0, stream>>>(Kp, Vp, Qp, Mws, zws, Aws, denw);
    k_out<<<dim3(32, 12), 256, 0, stream>>>(Qp, Vp, Aws, denw, Mws, zws,
                                            S0, Z0, out, Slast, Zlast);
}